// Round 1
// baseline (1929.558 us; speedup 1.0000x reference)
//
#include <hip/hip_runtime.h>
#include <math.h>

// Problem constants (compile-time)
#define DIMC   256
#define HH     48
#define WW     64
#define MROWS  (HH*WW)     // 3072
#define NHEADS 8
#define HD     32
#define KTAP   13
#define NTAPS  (KTAP*KTAP) // 169
#define DIL    3
#define NB     6           // KTAP/2
#define EPSLN  1e-5f
#define QSCALE 0.17677669529663687f  // 32^-0.5

// ---------------- window/bias start helpers (static arithmetic) -------------
__device__ __forceinline__ int win_start(int i, int L) {
    int imodd = i % DIL;
    if (i - NB * DIL < 0) return imodd;
    if (i + NB * DIL >= L) {
        int a = (L / DIL) * DIL;
        int b = L - a;
        if (imodd < b) return L - b + imodd - 2 * NB * DIL;
        return a + imodd - KTAP * DIL;
    }
    return i - NB * DIL;
}
__device__ __forceinline__ int pb_start(int i, int L) {
    if (i - NB * DIL < 0) return KTAP - 1 - i / DIL;
    if (i + NB * DIL >= L) return (L - 1 - i) / DIL;
    return NB;
}

// ---------------- input transpose: x (C, H*W) -> t (H*W, C) -----------------
__global__ void transpose_in_kernel(const float* __restrict__ x, float* __restrict__ t) {
    int m = blockIdx.x;         // row 0..3071
    int c = threadIdx.x;        // 0..255
    t[m * DIMC + c] = x[c * MROWS + m];
}

// ---------------- layernorm (optionally transposed store) -------------------
__global__ __launch_bounds__(256) void ln_kernel(const float* __restrict__ in,
                                                 const float* __restrict__ w,
                                                 const float* __restrict__ b,
                                                 float* __restrict__ out,
                                                 int transpose_out) {
    __shared__ float s1[4], s2[4];
    int m = blockIdx.x;
    int c = threadIdx.x;
    float v = in[m * DIMC + c];
    float a = v, q = v * v;
    #pragma unroll
    for (int o = 32; o > 0; o >>= 1) {
        a += __shfl_xor(a, o);
        q += __shfl_xor(q, o);
    }
    if ((threadIdx.x & 63) == 0) { s1[threadIdx.x >> 6] = a; s2[threadIdx.x >> 6] = q; }
    __syncthreads();
    float mean = (s1[0] + s1[1] + s1[2] + s1[3]) * (1.0f / DIMC);
    float var  = (s2[0] + s2[1] + s2[2] + s2[3]) * (1.0f / DIMC) - mean * mean;
    float r = (v - mean) * rsqrtf(var + EPSLN) * w[c] + b[c];
    if (transpose_out) out[c * MROWS + m] = r;
    else               out[m * DIMC + c] = r;
}

// ---------------- register-tiled fp32 GEMM: C = A * W^T + bias --------------
// A: (M,K) row-major.  W: (N,K) row-major.  Epilogue: 0=none, 1=gelu, 2=+res
template <int EPI>
__global__ __launch_bounds__(256) void gemm_kernel(const float* __restrict__ A,
                                                   const float* __restrict__ W,
                                                   const float* __restrict__ bias,
                                                   const float* __restrict__ res,
                                                   float* __restrict__ C,
                                                   int M, int N, int K) {
    const int BM = 64, BN = 64, BK = 16;
    __shared__ float As[BM][BK + 1];
    __shared__ float Ws[BN][BK + 1];
    int bm = blockIdx.y * BM, bn = blockIdx.x * BN;
    int tid = threadIdx.x;
    int tx = tid & 15, ty = tid >> 4;
    float acc[4][4] = {};
    for (int k0 = 0; k0 < K; k0 += BK) {
        #pragma unroll
        for (int i = 0; i < 4; i++) {
            int idx = tid + i * 256;
            int r = idx >> 4, cc = idx & 15;
            As[r][cc] = A[(bm + r) * K + k0 + cc];
            Ws[r][cc] = W[(bn + r) * K + k0 + cc];
        }
        __syncthreads();
        #pragma unroll
        for (int kk = 0; kk < BK; kk++) {
            float av[4], wv[4];
            #pragma unroll
            for (int i = 0; i < 4; i++) av[i] = As[ty * 4 + i][kk];
            #pragma unroll
            for (int j = 0; j < 4; j++) wv[j] = Ws[tx * 4 + j][kk];
            #pragma unroll
            for (int i = 0; i < 4; i++)
                #pragma unroll
                for (int j = 0; j < 4; j++) acc[i][j] += av[i] * wv[j];
        }
        __syncthreads();
    }
    #pragma unroll
    for (int i = 0; i < 4; i++) {
        int m = bm + ty * 4 + i;
        #pragma unroll
        for (int j = 0; j < 4; j++) {
            int n = bn + tx * 4 + j;
            float v = acc[i][j] + bias[n];
            if (EPI == 1) v = v * 0.5f * (1.0f + erff(v * 0.70710678118654752f));
            if (EPI == 2) v += res[m * N + n];
            C[m * N + n] = v;
        }
    }
}

// ---------------- neighborhood attention ------------------------------------
// qkv: (3072, 768)  cols: q = n*32+d, k = 256+n*32+d, v = 512+n*32+d
// out: (3072, 256)  col = n*32+d
__global__ __launch_bounds__(256) void attn_kernel(const float* __restrict__ qkv,
                                                   const float* __restrict__ rpb,
                                                   const float* __restrict__ lrm,
                                                   float* __restrict__ out) {
    __shared__ float qs[4][HD];
    __shared__ float ps[4][NTAPS + 7];
    int wave = threadIdx.x >> 6;
    int lane = threadIdx.x & 63;
    int gid = blockIdx.x * 4 + wave;   // 0..24575
    int n = gid & 7;
    int m = gid >> 3;                  // 0..3071
    int h = m / WW, w = m % WW;

    if (lane < HD) qs[wave][lane] = qkv[m * 768 + n * HD + lane] * QSCALE;
    __syncthreads();

    int sh = win_start(h, HH), sw = win_start(w, WW);
    int ph = pb_start(h, HH), pw = pb_start(w, WW);

    // Phase 1: scores
    float smax = -1e30f;
    for (int t = lane; t < NTAPS; t += 64) {
        int ti = t / KTAP, tj = t % KTAP;
        int ihr = sh + DIL * ti, iwc = sw + DIL * tj;
        const float* krow = qkv + (ihr * WW + iwc) * 768 + DIMC + n * HD;
        float s = 0.0f;
        #pragma unroll
        for (int d = 0; d < HD; d++) s += qs[wave][d] * krow[d];
        s += rpb[(n * 25 + ph + ti) * 25 + (pw + tj)];
        float dx = (float)(tj - NB), dy = (float)(ti - NB);
        float g = __expf(-(dx * dx + dy * dy) * (1.0f / 162.0f));
        s *= (g + lrm[t] * 10.0f);   // lrm / SC, SC = 0.1
        ps[wave][t] = s;
        smax = fmaxf(smax, s);
    }
    #pragma unroll
    for (int o = 32; o > 0; o >>= 1) smax = fmaxf(smax, __shfl_xor(smax, o));

    // Phase 2: exp + sum
    float ssum = 0.0f;
    for (int t = lane; t < NTAPS; t += 64) {
        float e = __expf(ps[wave][t] - smax);
        ps[wave][t] = e;
        ssum += e;
    }
    #pragma unroll
    for (int o = 32; o > 0; o >>= 1) ssum += __shfl_xor(ssum, o);
    float inv = 1.0f / ssum;
    __syncthreads();

    // Phase 3: PV  (lanes = d 0..31  x  tap parity)
    int d = lane & 31, hf = lane >> 5;
    float acc = 0.0f;
    for (int t = hf; t < NTAPS; t += 2) {
        int ti = t / KTAP, tj = t % KTAP;
        int ihr = sh + DIL * ti, iwc = sw + DIL * tj;
        acc += ps[wave][t] * qkv[(ihr * WW + iwc) * 768 + 2 * DIMC + n * HD + d];
    }
    acc += __shfl_xor(acc, 32);
    if (hf == 0) out[m * DIMC + n * HD + d] = acc * inv;
}

// ---------------- launch -----------------------------------------------------
extern "C" void kernel_launch(void* const* d_in, const int* in_sizes, int n_in,
                              void* d_out, int out_size, void* d_ws, size_t ws_size,
                              hipStream_t stream) {
    const float* x      = (const float*)d_in[0];
    const float* ln1_w  = (const float*)d_in[1];
    const float* ln1_b  = (const float*)d_in[2];
    const float* qkv_w  = (const float*)d_in[3];
    const float* qkv_b  = (const float*)d_in[4];
    const float* rpb    = (const float*)d_in[5];
    const float* lr_m   = (const float*)d_in[6];
    const float* proj_w = (const float*)d_in[7];
    const float* proj_b = (const float*)d_in[8];
    const float* ln2_w  = (const float*)d_in[9];
    const float* ln2_b  = (const float*)d_in[10];
    const float* fc1_w  = (const float*)d_in[11];
    const float* fc1_b  = (const float*)d_in[12];
    const float* fc2_w  = (const float*)d_in[13];
    const float* fc2_b  = (const float*)d_in[14];
    const float* nf_w   = (const float*)d_in[15];
    const float* nf_b   = (const float*)d_in[16];
    float* out = (float*)d_out;

    float* ws = (float*)d_ws;
    float* t        = ws;                      // 3072*256
    float* y        = t + MROWS * DIMC;        // 3072*256
    float* attn_out = y + MROWS * DIMC;        // 3072*256
    float* qkvb     = attn_out + MROWS * DIMC; // 3072*768
    float* m1       = qkvb + MROWS * 768;      // 3072*1024

    transpose_in_kernel<<<MROWS, 256, 0, stream>>>(x, t);

    for (int l = 0; l < 6; l++) {
        const float* qw = qkv_w  + (size_t)l * 768 * 256;
        const float* qb = qkv_b  + (size_t)l * 768;
        const float* pw = proj_w + (size_t)l * 256 * 256;
        const float* pb = proj_b + (size_t)l * 256;
        const float* f1w = fc1_w + (size_t)l * 1024 * 256;
        const float* f1b = fc1_b + (size_t)l * 1024;
        const float* f2w = fc2_w + (size_t)l * 256 * 1024;
        const float* f2b = fc2_b + (size_t)l * 256;
        const float* rp  = rpb   + (size_t)l * NHEADS * 25 * 25;
        const float* lm  = lr_m  + (size_t)l * NTAPS;

        ln_kernel<<<MROWS, 256, 0, stream>>>(t, ln1_w + l * 256, ln1_b + l * 256, y, 0);
        gemm_kernel<0><<<dim3(768 / 64, MROWS / 64), 256, 0, stream>>>(
            y, qw, qb, nullptr, qkvb, MROWS, 768, 256);
        attn_kernel<<<(MROWS * NHEADS) / 4, 256, 0, stream>>>(qkvb, rp, lm, attn_out);
        gemm_kernel<2><<<dim3(256 / 64, MROWS / 64), 256, 0, stream>>>(
            attn_out, pw, pb, t, t, MROWS, 256, 256);
        ln_kernel<<<MROWS, 256, 0, stream>>>(t, ln2_w + l * 256, ln2_b + l * 256, y, 0);
        gemm_kernel<1><<<dim3(1024 / 64, MROWS / 64), 256, 0, stream>>>(
            y, f1w, f1b, nullptr, m1, MROWS, 1024, 256);
        gemm_kernel<2><<<dim3(256 / 64, MROWS / 64), 256, 0, stream>>>(
            m1, f2w, f2b, t, t, MROWS, 256, 1024);
    }

    ln_kernel<<<MROWS, 256, 0, stream>>>(t, nf_w, nf_b, out, 1);
}

// Round 2
// 807.755 us; speedup vs baseline: 2.3888x; 2.3888x over previous
//
#include <hip/hip_runtime.h>
#include <hip/hip_bf16.h>
#include <math.h>

// Problem constants (compile-time)
#define DIMC   256
#define HH     48
#define WW     64
#define MROWS  (HH*WW)     // 3072
#define NHEADS 8
#define HD     32
#define KTAP   13
#define NTAPS  (KTAP*KTAP) // 169
#define DIL    3
#define NB     6           // KTAP/2
#define EPSLN  1e-5f
#define QSCALE 0.17677669529663687f  // 32^-0.5

typedef __attribute__((ext_vector_type(8))) short bf16x8;
typedef __attribute__((ext_vector_type(4))) float f32x4;

// ---------------- window/bias start helpers (static arithmetic) -------------
__device__ __forceinline__ int win_start(int i, int L) {
    int imodd = i % DIL;
    if (i - NB * DIL < 0) return imodd;
    if (i + NB * DIL >= L) {
        int a = (L / DIL) * DIL;
        int b = L - a;
        if (imodd < b) return L - b + imodd - 2 * NB * DIL;
        return a + imodd - KTAP * DIL;
    }
    return i - NB * DIL;
}
__device__ __forceinline__ int pb_start(int i, int L) {
    if (i - NB * DIL < 0) return KTAP - 1 - i / DIL;
    if (i + NB * DIL >= L) return (L - 1 - i) / DIL;
    return NB;
}

// ---------------- fp32 -> bf16 conversion (weights) --------------------------
__global__ __launch_bounds__(256) void cvt_bf16_kernel(const float* __restrict__ in,
                                                       __hip_bfloat16* __restrict__ out,
                                                       int n4) {
    int i = blockIdx.x * 256 + threadIdx.x;
    if (i >= n4) return;
    float4 v = ((const float4*)in)[i];
    union { __hip_bfloat16 h[4]; ushort4 u; } p;
    p.h[0] = __float2bfloat16(v.x);
    p.h[1] = __float2bfloat16(v.y);
    p.h[2] = __float2bfloat16(v.z);
    p.h[3] = __float2bfloat16(v.w);
    ((ushort4*)out)[i] = p.u;
}

// ---------------- input transpose: x (C, H*W) -> t (H*W, C) -----------------
__global__ void transpose_in_kernel(const float* __restrict__ x, float* __restrict__ t) {
    int m = blockIdx.x;
    int c = threadIdx.x;
    t[m * DIMC + c] = x[c * MROWS + m];
}

// ---------------- layernorm; OutT float or bf16; optional transposed store ---
template <typename OutT, int TRANS>
__global__ __launch_bounds__(256) void ln_kernel(const float* __restrict__ in,
                                                 const float* __restrict__ w,
                                                 const float* __restrict__ b,
                                                 OutT* __restrict__ out) {
    __shared__ float s1[4], s2[4];
    int m = blockIdx.x;
    int c = threadIdx.x;
    float v = in[m * DIMC + c];
    float a = v, q = v * v;
    #pragma unroll
    for (int o = 32; o > 0; o >>= 1) {
        a += __shfl_xor(a, o);
        q += __shfl_xor(q, o);
    }
    if ((threadIdx.x & 63) == 0) { s1[threadIdx.x >> 6] = a; s2[threadIdx.x >> 6] = q; }
    __syncthreads();
    float mean = (s1[0] + s1[1] + s1[2] + s1[3]) * (1.0f / DIMC);
    float var  = (s2[0] + s2[1] + s2[2] + s2[3]) * (1.0f / DIMC) - mean * mean;
    float r = (v - mean) * rsqrtf(var + EPSLN) * w[c] + b[c];
    if (TRANS) {
        out[c * MROWS + m] = (OutT)r;
    } else {
        if constexpr (sizeof(OutT) == 2) out[m * DIMC + c] = __float2bfloat16(r);
        else                             out[m * DIMC + c] = r;
    }
}

// ---------------- bf16 MFMA GEMM: C = A * W^T + bias -------------------------
// A: (M,K) bf16 row-major.  W: (N,K) bf16 row-major.
// EPI: 0=none, 1=gelu(exact), 2=+res (fp32).  OutT: float or __hip_bfloat16.
#define LDP 72  // padded LDS row stride in bf16 elems (144 B -> 2-way alias, free)
template <int EPI, typename OutT>
__global__ __launch_bounds__(256) void gemm_mfma_kernel(const __hip_bfloat16* __restrict__ A,
                                                        const __hip_bfloat16* __restrict__ Wt,
                                                        const float* __restrict__ bias,
                                                        const float* __restrict__ res,
                                                        OutT* __restrict__ C,
                                                        int M, int N, int K) {
    __shared__ __hip_bfloat16 As[64][LDP];
    __shared__ __hip_bfloat16 Ws[64][LDP];
    int tid = threadIdx.x;
    int bm = blockIdx.y * 64, bn = blockIdx.x * 64;
    int lane = tid & 63, wid = tid >> 6;
    int wr = wid >> 1, wc = wid & 1;      // wave's 32x32 quadrant
    int fr = lane & 15, fq = lane >> 4;   // fragment row/col, k-group
    f32x4 acc[2][2] = {};

    for (int k0 = 0; k0 < K; k0 += 64) {
        #pragma unroll
        for (int i = 0; i < 4; i++) {
            int idx = tid + i * 256;          // 0..1023
            int r = idx >> 4, c = (idx & 15) << 2;
            *(uint2*)&As[r][c] = *(const uint2*)&A[(size_t)(bm + r) * K + k0 + c];
            *(uint2*)&Ws[r][c] = *(const uint2*)&Wt[(size_t)(bn + r) * K + k0 + c];
        }
        __syncthreads();
        #pragma unroll
        for (int kk = 0; kk < 2; kk++) {
            int kb = kk * 32 + fq * 8;
            bf16x8 af[2], bfr[2];
            #pragma unroll
            for (int i = 0; i < 2; i++) {
                union { uint2 u[2]; bf16x8 v; } ua, ub;
                const __hip_bfloat16* pa = &As[wr * 32 + i * 16 + fr][kb];
                ua.u[0] = *(const uint2*)pa;
                ua.u[1] = *(const uint2*)(pa + 4);
                af[i] = ua.v;
                const __hip_bfloat16* pb = &Ws[wc * 32 + i * 16 + fr][kb];
                ub.u[0] = *(const uint2*)pb;
                ub.u[1] = *(const uint2*)(pb + 4);
                bfr[i] = ub.v;
            }
            #pragma unroll
            for (int i = 0; i < 2; i++)
                #pragma unroll
                for (int j = 0; j < 2; j++)
                    acc[i][j] = __builtin_amdgcn_mfma_f32_16x16x32_bf16(
                        af[i], bfr[j], acc[i][j], 0, 0, 0);
        }
        __syncthreads();
    }
    #pragma unroll
    for (int i = 0; i < 2; i++) {
        int mbase = bm + wr * 32 + i * 16 + fq * 4;
        #pragma unroll
        for (int j = 0; j < 2; j++) {
            int n = bn + wc * 32 + j * 16 + fr;
            float bv = bias[n];
            #pragma unroll
            for (int r = 0; r < 4; r++) {
                int m = mbase + r;
                float v = acc[i][j][r] + bv;
                if (EPI == 1) v = v * 0.5f * (1.0f + erff(v * 0.70710678118654752f));
                if (EPI == 2) v += res[(size_t)m * N + n];
                if constexpr (sizeof(OutT) == 2) C[(size_t)m * N + n] = __float2bfloat16(v);
                else                             C[(size_t)m * N + n] = v;
            }
        }
    }
}

// ---------------- neighborhood attention ------------------------------------
// qkv: (3072, 768) fp32.  out: (3072, 256) bf16.
__global__ __launch_bounds__(256) void attn_kernel(const float* __restrict__ qkv,
                                                   const float* __restrict__ rpb,
                                                   const float* __restrict__ lrm,
                                                   __hip_bfloat16* __restrict__ out) {
    __shared__ float qs[4][HD];
    __shared__ float ps[4][NTAPS + 7];
    __shared__ int   voff[4][NTAPS + 7];
    int wave = threadIdx.x >> 6;
    int lane = threadIdx.x & 63;
    int gid = blockIdx.x * 4 + wave;
    int n = gid & 7;
    int m = gid >> 3;
    int h = m / WW, w = m % WW;

    if (lane < HD) qs[wave][lane] = qkv[m * 768 + n * HD + lane] * QSCALE;
    __syncthreads();

    int sh = win_start(h, HH), sw = win_start(w, WW);
    int ph = pb_start(h, HH), pw = pb_start(w, WW);

    // Phase 1: scores (float4 K loads), cache per-tap row offsets
    const float4* q4 = (const float4*)qs[wave];
    float smax = -1e30f;
    for (int t = lane; t < NTAPS; t += 64) {
        int ti = t / KTAP, tj = t - KTAP * ti;
        int off = ((sh + DIL * ti) * WW + (sw + DIL * tj)) * 768;
        voff[wave][t] = off;
        const float4* kr = (const float4*)(qkv + off + DIMC + n * HD);
        float s = 0.0f;
        #pragma unroll
        for (int d4 = 0; d4 < 8; d4++) {
            float4 kv = kr[d4];
            float4 qv = q4[d4];
            s += qv.x * kv.x + qv.y * kv.y + qv.z * kv.z + qv.w * kv.w;
        }
        s += rpb[(n * 25 + ph + ti) * 25 + (pw + tj)];
        float dx = (float)(tj - NB), dy = (float)(ti - NB);
        float g = __expf(-(dx * dx + dy * dy) * (1.0f / 162.0f));
        s *= (g + lrm[t] * 10.0f);   // lrm / SC, SC = 0.1
        ps[wave][t] = s;
        smax = fmaxf(smax, s);
    }
    #pragma unroll
    for (int o = 32; o > 0; o >>= 1) smax = fmaxf(smax, __shfl_xor(smax, o));

    // Phase 2: exp + sum
    float ssum = 0.0f;
    for (int t = lane; t < NTAPS; t += 64) {
        float e = __expf(ps[wave][t] - smax);
        ps[wave][t] = e;
        ssum += e;
    }
    #pragma unroll
    for (int o = 32; o > 0; o >>= 1) ssum += __shfl_xor(ssum, o);
    float inv = 1.0f / ssum;
    __syncthreads();

    // Phase 3: PV.  lane -> (tap group g = lane>>3, d4 = lane&7 covering 4 d's)
    int d4 = lane & 7, g = lane >> 3;
    float a0 = 0.0f, a1 = 0.0f, a2 = 0.0f, a3 = 0.0f;
    for (int t = g; t < NTAPS; t += 8) {
        float p = ps[wave][t];
        const float4* vr = (const float4*)(qkv + voff[wave][t] + 2 * DIMC + n * HD);
        float4 v = vr[d4];
        a0 += p * v.x; a1 += p * v.y; a2 += p * v.z; a3 += p * v.w;
    }
    #pragma unroll
    for (int o = 8; o < 64; o <<= 1) {
        a0 += __shfl_xor(a0, o);
        a1 += __shfl_xor(a1, o);
        a2 += __shfl_xor(a2, o);
        a3 += __shfl_xor(a3, o);
    }
    if (g == 0) {
        union { __hip_bfloat16 h[4]; ushort4 u; } p;
        p.h[0] = __float2bfloat16(a0 * inv);
        p.h[1] = __float2bfloat16(a1 * inv);
        p.h[2] = __float2bfloat16(a2 * inv);
        p.h[3] = __float2bfloat16(a3 * inv);
        *(ushort4*)&out[m * DIMC + n * HD + d4 * 4] = p.u;
    }
}

// ---------------- launch -----------------------------------------------------
extern "C" void kernel_launch(void* const* d_in, const int* in_sizes, int n_in,
                              void* d_out, int out_size, void* d_ws, size_t ws_size,
                              hipStream_t stream) {
    const float* x      = (const float*)d_in[0];
    const float* ln1_w  = (const float*)d_in[1];
    const float* ln1_b  = (const float*)d_in[2];
    const float* qkv_w  = (const float*)d_in[3];
    const float* qkv_b  = (const float*)d_in[4];
    const float* rpb    = (const float*)d_in[5];
    const float* lr_m   = (const float*)d_in[6];
    const float* proj_w = (const float*)d_in[7];
    const float* proj_b = (const float*)d_in[8];
    const float* ln2_w  = (const float*)d_in[9];
    const float* ln2_b  = (const float*)d_in[10];
    const float* fc1_w  = (const float*)d_in[11];
    const float* fc1_b  = (const float*)d_in[12];
    const float* fc2_w  = (const float*)d_in[13];
    const float* fc2_b  = (const float*)d_in[14];
    const float* nf_w   = (const float*)d_in[15];
    const float* nf_b   = (const float*)d_in[16];
    float* out = (float*)d_out;

    // workspace layout (bytes; all 256-aligned)
    char* ws = (char*)d_ws;
    float*          t        = (float*)ws;                               //  3 MB
    float*          qkvb     = (float*)(ws + 3145728);                   //  9.4 MB
    __hip_bfloat16* y        = (__hip_bfloat16*)(ws + 12582912);         //  1.5 MB
    __hip_bfloat16* attn_out = (__hip_bfloat16*)(ws + 14155776);         //  1.5 MB
    __hip_bfloat16* m1       = (__hip_bfloat16*)(ws + 15728640);         //  6 MB
    __hip_bfloat16* qkv_wb   = (__hip_bfloat16*)(ws + 22020096);         //  2.25 MB
    __hip_bfloat16* proj_wb  = (__hip_bfloat16*)(ws + 24379392);         //  0.75 MB
    __hip_bfloat16* fc1_wb   = (__hip_bfloat16*)(ws + 25165824);         //  3 MB
    __hip_bfloat16* fc2_wb   = (__hip_bfloat16*)(ws + 28311552);         //  3 MB

    // one-shot weight conversions (all 6 layers)
    {
        int n;
        n = 6 * 768 * 256 / 4;
        cvt_bf16_kernel<<<(n + 255) / 256, 256, 0, stream>>>(qkv_w, qkv_wb, n);
        n = 6 * 256 * 256 / 4;
        cvt_bf16_kernel<<<(n + 255) / 256, 256, 0, stream>>>(proj_w, proj_wb, n);
        n = 6 * 1024 * 256 / 4;
        cvt_bf16_kernel<<<(n + 255) / 256, 256, 0, stream>>>(fc1_w, fc1_wb, n);
        n = 6 * 256 * 1024 / 4;
        cvt_bf16_kernel<<<(n + 255) / 256, 256, 0, stream>>>(fc2_w, fc2_wb, n);
    }

    transpose_in_kernel<<<MROWS, 256, 0, stream>>>(x, t);

    for (int l = 0; l < 6; l++) {
        const __hip_bfloat16* qw  = qkv_wb  + (size_t)l * 768 * 256;
        const __hip_bfloat16* pw  = proj_wb + (size_t)l * 256 * 256;
        const __hip_bfloat16* f1w = fc1_wb  + (size_t)l * 1024 * 256;
        const __hip_bfloat16* f2w = fc2_wb  + (size_t)l * 256 * 1024;
        const float* qb  = qkv_b  + (size_t)l * 768;
        const float* pb  = proj_b + (size_t)l * 256;
        const float* f1b = fc1_b  + (size_t)l * 1024;
        const float* f2b = fc2_b  + (size_t)l * 256;
        const float* rp  = rpb    + (size_t)l * NHEADS * 25 * 25;
        const float* lm  = lr_m   + (size_t)l * NTAPS;

        ln_kernel<__hip_bfloat16, 0><<<MROWS, 256, 0, stream>>>(
            t, ln1_w + l * 256, ln1_b + l * 256, y);
        gemm_mfma_kernel<0, float><<<dim3(768 / 64, MROWS / 64), 256, 0, stream>>>(
            y, qw, qb, nullptr, qkvb, MROWS, 768, 256);
        attn_kernel<<<(MROWS * NHEADS) / 4, 256, 0, stream>>>(qkvb, rp, lm, attn_out);
        gemm_mfma_kernel<2, float><<<dim3(256 / 64, MROWS / 64), 256, 0, stream>>>(
            attn_out, pw, pb, t, t, MROWS, 256, 256);
        ln_kernel<__hip_bfloat16, 0><<<MROWS, 256, 0, stream>>>(
            t, ln2_w + l * 256, ln2_b + l * 256, y);
        gemm_mfma_kernel<1, __hip_bfloat16><<<dim3(1024 / 64, MROWS / 64), 256, 0, stream>>>(
            y, f1w, f1b, nullptr, m1, MROWS, 1024, 256);
        gemm_mfma_kernel<2, float><<<dim3(256 / 64, MROWS / 64), 256, 0, stream>>>(
            m1, f2w, f2b, t, t, MROWS, 256, 1024);
    }

    ln_kernel<float, 1><<<MROWS, 256, 0, stream>>>(t, nf_w, nf_b, out);
}